// Round 7
// baseline (851.146 us; speedup 1.0000x reference)
//
#include <hip/hip_runtime.h>
#include <hip/hip_bf16.h>

// Problem: B=4, T=2048, C=2048, H=16, HD=128. BT=8192, 3C=6144.
// Pipeline: cvt x->bf16; W_attn^T, W_proj^T (bf16); GEMM1(qkv + bias + rope(k,v)
// + scale(q, incl. log2e) + scatter: q,k -> (B,H,T,HD), v -> (B,H,HD,T) directly);
// flash attn (causal, online softmax in exp2 domain, defer-max THR=8, K/V LDS
// double-buffer with cross-barrier prefetch) -> bf16 attn_out (B,T,C);
// GEMM2(proj + bias) -> fp32 out.

#define DEVI __device__ __forceinline__

typedef short  bf16x8 __attribute__((ext_vector_type(8)));
typedef float  f32x4  __attribute__((ext_vector_type(4)));
typedef ushort us8    __attribute__((ext_vector_type(8)));
typedef ushort us4    __attribute__((ext_vector_type(4)));

DEVI ushort f2b(float f) {
    __hip_bfloat16 h = __float2bfloat16(f);
    union { __hip_bfloat16 b; ushort u; } c; c.b = h; return c.u;
}

DEVI void gload16(const void* g, void* l) {
    __builtin_amdgcn_global_load_lds((const __attribute__((address_space(1))) void*)g,
                                     (__attribute__((address_space(3))) void*)l,
                                     16, 0, 0);
}

DEVI f32x4 mfma16(bf16x8 a, bf16x8 b, f32x4 c) {
    return __builtin_amdgcn_mfma_f32_16x16x32_bf16(a, b, c, 0, 0, 0);
}

DEVI bf16x8 ldsr(const ushort* p) { return *(const bf16x8*)p; }

// ---------------------------------------------------------------- cvt fp32->bf16
__global__ void k_cvt(const float* __restrict__ in, ushort* __restrict__ out, int n8) {
    int i = blockIdx.x * blockDim.x + threadIdx.x;
    if (i >= n8) return;
    const float4* p = (const float4*)in + (size_t)i * 2;
    float4 a = p[0], b = p[1];
    us8 v;
    v[0] = f2b(a.x); v[1] = f2b(a.y); v[2] = f2b(a.z); v[3] = f2b(a.w);
    v[4] = f2b(b.x); v[5] = f2b(b.y); v[6] = f2b(b.z); v[7] = f2b(b.w);
    *(us8*)(out + (size_t)i * 8) = v;
}

// -------------------------------------------- transpose+cvt W (R x Cc fp32) -> (Cc x R bf16)
__global__ void k_tr_w(const float* __restrict__ in, ushort* __restrict__ out, int R, int Cc) {
    __shared__ float t[32][33];
    int tx = threadIdx.x & 31, ty = threadIdx.x >> 5;     // ty 0..7
    int c0 = blockIdx.x * 32, r0 = blockIdx.y * 32;
    #pragma unroll
    for (int i = 0; i < 4; ++i) {
        int r = ty + i * 8;
        t[r][tx] = in[(size_t)(r0 + r) * Cc + c0 + tx];
    }
    __syncthreads();
    #pragma unroll
    for (int i = 0; i < 4; ++i) {
        int c = ty + i * 8;
        out[(size_t)(c0 + c) * R + r0 + tx] = f2b(t[tx][c]);
    }
}

// ---------------------------------------------------------------- GEMM (bf16 MFMA)
// A: M x K row-major bf16.  Bt: N x K row-major bf16 (i.e. B^T).  BM=BN=128, BK=32.
// 256 threads = 4 waves in 2x2; each wave 64x64 = 4x4 frags of 16x16.
// LDS tiles [128 rows][32 k]; swizzle: phys 16B-chunk = logical ^ ((row>>1)&3)
//   -> bank-group (4*row + chunk) mod 8 covers all 8 groups twice per 16 rows
//   -> 2-way (free, m136).
// No setprio here: T5 is ~0/negative on 2-phase lockstep GEMM (m190).
// EPI 0: qkv epilogue (bias + rope k,v + scale q (1/sqrt(HD)*log2e) + scatter;
//        q,k -> (B,H,T,HD); v -> (B,H,HD,T) transposed, vectorized 8B stores)
// EPI 1: proj epilogue (bias, fp32 out)
template<int EPI>
__global__ __launch_bounds__(256) void k_gemm(
    const ushort* __restrict__ A, const ushort* __restrict__ Bt,
    int M, int Ntn, int K, int nwg_div8,
    const float* __restrict__ bias,
    ushort* __restrict__ qOut, ushort* __restrict__ kOut, ushort* __restrict__ vOut,
    const float* __restrict__ cosT, const float* __restrict__ sinT,
    float* __restrict__ outF)
{
    __shared__ ushort sA[2][4096];
    __shared__ ushort sB[2][4096];

    int bid = blockIdx.x;
    int wg  = (bid & 7) * nwg_div8 + (bid >> 3);   // XCD swizzle (nwg % 8 == 0)
    int n_t = wg % Ntn, m_t = wg / Ntn;
    int m0 = m_t * 128, n0 = n_t * 128;
    int tid = threadIdx.x;
    int lane = tid & 63, w = tid >> 6;
    int lrow = lane & 15, lk = lane >> 4;
    int wr = w >> 1, wc = w & 1;

    const ushort* Abase = A  + (size_t)m0 * K;
    const ushort* Bbase = Bt + (size_t)n0 * K;

    // staging decode: 16B slot s: row = s>>2, physical chunk = s&3,
    // global chunk = (s&3) ^ ((row>>1)&3)  (inverse-swizzled SOURCE, linear dest)
    int s0 = tid, s1 = 256 + tid;
    int r0 = s0 >> 2, c0 = (s0 & 3) ^ ((r0 >> 1) & 3);
    int r1 = s1 >> 2, c1 = (s1 & 3) ^ ((r1 >> 1) & 3);

    f32x4 acc[4][4];
    #pragma unroll
    for (int i = 0; i < 4; ++i)
        #pragma unroll
        for (int j = 0; j < 4; ++j) acc[i][j] = (f32x4)0.f;

    auto stage = [&](int buf, int kt) {
        int k0 = kt * 32;
        const ushort* ga = Abase + k0;
        const ushort* gb = Bbase + k0;
        gload16(ga + (size_t)r0 * K + c0 * 8, &sA[buf][s0 * 8]);
        gload16(ga + (size_t)r1 * K + c1 * 8, &sA[buf][s1 * 8]);
        gload16(gb + (size_t)r0 * K + c0 * 8, &sB[buf][s0 * 8]);
        gload16(gb + (size_t)r1 * K + c1 * 8, &sB[buf][s1 * 8]);
    };

    stage(0, 0);
    __syncthreads();
    int nk = K >> 5;
    for (int kt = 0; kt < nk; ++kt) {
        int cur = kt & 1;
        if (kt + 1 < nk) stage(cur ^ 1, kt + 1);
        bf16x8 af[4], bfr[4];
        #pragma unroll
        for (int m = 0; m < 4; ++m) {
            int row = wr * 64 + m * 16 + lrow;
            int pc = lk ^ ((row >> 1) & 3);
            af[m] = ldsr(&sA[cur][row * 32 + pc * 8]);
        }
        #pragma unroll
        for (int n = 0; n < 4; ++n) {
            int row = wc * 64 + n * 16 + lrow;
            int pc = lk ^ ((row >> 1) & 3);
            bfr[n] = ldsr(&sB[cur][row * 32 + pc * 8]);
        }
        #pragma unroll
        for (int m = 0; m < 4; ++m)
            #pragma unroll
            for (int n = 0; n < 4; ++n)
                acc[m][n] = mfma16(af[m], bfr[n], acc[m][n]);
        __syncthreads();
    }

    if (EPI == 1) {
        int N = Ntn * 128;
        #pragma unroll
        for (int m = 0; m < 4; ++m) {
            int rowb = m0 + wr * 64 + m * 16 + lk * 4;
            #pragma unroll
            for (int n = 0; n < 4; ++n) {
                int col = n0 + wc * 64 + n * 16 + lrow;
                float bb = bias[col];
                #pragma unroll
                for (int j = 0; j < 4; ++j)
                    outF[(size_t)(rowb + j) * N + col] = acc[m][n][j] + bb;
            }
        }
    } else {
        // 1/sqrt(128) * log2(e): softmax runs in exp2 domain downstream.
        const float SCALE = 0.08838834764831845f * 1.4426950408889634f;
        // which/h are frag-uniform: n-tiles are 128-wide and QKV segment
        // boundaries are 2048-aligned.
        #pragma unroll
        for (int m = 0; m < 4; ++m) {
            #pragma unroll
            for (int n = 0; n < 4; ++n) {
                int col = n0 + wc * 64 + n * 16 + lrow;    // 0..6143
                int which = col >> 11;                      // 0=q 1=k 2=v
                int h = (col >> 7) & 15;
                int d = col & 127;
                float bb = bias[col];
                int rowb = m0 + wr * 64 + m * 16 + lk * 4;  // t base (mult of 4)
                int b = rowb >> 11, tb = rowb & 2047;       // no b-crossing in j
                int bh = (b << 4) | h;
                float val[4], oth[4];
                #pragma unroll
                for (int j = 0; j < 4; ++j) val[j] = acc[m][n][j] + bb;
                #pragma unroll
                for (int j = 0; j < 4; ++j) oth[j] = __shfl_xor(val[j], 1); // rope partner (col^1)
                if (which == 0) {
                    size_t offb = (((size_t)bh * 2048 + tb) << 7) | d;      // (B,H,T,HD)
                    #pragma unroll
                    for (int j = 0; j < 4; ++j)
                        qOut[offb + ((size_t)j << 7)] = f2b(val[j] * SCALE);
                } else if (which == 1) {
                    size_t offb = (((size_t)bh * 2048 + tb) << 7) | d;      // (B,H,T,HD)
                    #pragma unroll
                    for (int j = 0; j < 4; ++j) {
                        int t = tb + j;
                        float c = cosT[t * 64 + (d >> 1)];
                        float s = sinT[t * 64 + (d >> 1)];
                        float r = (d & 1) ? (val[j] * c + oth[j] * s)
                                          : (val[j] * c - oth[j] * s);
                        kOut[offb + ((size_t)j << 7)] = f2b(r);
                    }
                } else {
                    // v -> (B,H,HD,T); j walks contiguous t -> one 8B store
                    us4 rv;
                    #pragma unroll
                    for (int j = 0; j < 4; ++j) {
                        int t = tb + j;
                        float c = cosT[t * 64 + (d >> 1)];
                        float s = sinT[t * 64 + (d >> 1)];
                        float r = (d & 1) ? (val[j] * c + oth[j] * s)
                                          : (val[j] * c - oth[j] * s);
                        rv[j] = f2b(r);
                    }
                    *(us4*)(vOut + (((size_t)bh << 18) + ((size_t)d << 11) + tb)) = rv;
                }
            }
        }
    }
}

// ---------------------------------------------------------------- flash attention
// grid 1024: bh = bid&63, qt = 15-(bid>>6) (heavy q-tiles first). Block: 4 waves,
// each wave 32 q-rows (QB=128). K-tiles of 64. Q in regs; K/V double-buffered in
// LDS: K [64][128] (swz ^row&15), Vt [128][64] (swz ^row&7); P per-wave [32][64]
// (swz ^row&7). ONE barrier per tile; stage(t+1) issued after the barrier so the
// global_load_lds stay in flight under compute(t) (m97/m214 pattern). Online
// softmax in exp2 domain (q pre-scaled by log2e). Causal mask only on the 2
// diagonal tiles. T13 defer-max: skip O-rescale when wave max-growth <= 8.
// setprio kept on MFMA clusters: T5 +4-7% on attn (m191).
__global__ __launch_bounds__(256) void k_attn(
    const ushort* __restrict__ Q, const ushort* __restrict__ Kb,
    const ushort* __restrict__ Vt, ushort* __restrict__ O)
{
    __shared__ ushort smem[40960];   // 80KB: K dbuf 2x16K | V dbuf 2x16K | P 4x4K
    int bid = blockIdx.x;
    int bh = bid & 63;
    int qt = 15 - (bid >> 6);
    int q0 = qt << 7;
    int b = bh >> 4, h = bh & 15;
    int tid = threadIdx.x, lane = tid & 63, w = tid >> 6;
    int lrow = lane & 15, lk = lane >> 4;

    const ushort* Qb  = Q  + ((size_t)bh << 18);
    const ushort* Kbb = Kb + ((size_t)bh << 18);
    const ushort* Vbb = Vt + ((size_t)bh << 18);

    ushort* sP = smem + 32768 + w * 2048;

    // ---- stage Q tile (128x128 = 32KB) through the two K buffers, pull to regs
    #pragma unroll
    for (int i = 0; i < 8; ++i) {
        int s = i * 256 + tid;
        int qr = s >> 4, pc = s & 15, dc = pc ^ (qr & 15);
        gload16(Qb + ((size_t)(q0 + qr) << 7) + dc * 8, smem + s * 8);
    }
    __syncthreads();
    bf16x8 qf[2][4];
    #pragma unroll
    for (int rf = 0; rf < 2; ++rf)
        #pragma unroll
        for (int ds = 0; ds < 4; ++ds) {
            int qr = w * 32 + rf * 16 + lrow;
            int pc = (ds * 4 + lk) ^ (qr & 15);
            qf[rf][ds] = ldsr(smem + qr * 128 + pc * 8);
        }
    __syncthreads();   // all waves done with Q region before stage(0) overwrites

    auto stageKV = [&](int buf, int kt) {
        int k0 = kt * 64;
        ushort* sKb = smem + buf * 8192;
        ushort* sVb = smem + 16384 + buf * 8192;
        #pragma unroll
        for (int i = 0; i < 4; ++i) {
            int s = i * 256 + tid;
            int kr = s >> 4, pc = s & 15, dc = pc ^ (kr & 15);
            gload16(Kbb + ((size_t)(k0 + kr) << 7) + dc * 8, sKb + s * 8);
        }
        #pragma unroll
        for (int i = 0; i < 4; ++i) {
            int s = i * 256 + tid;
            int dr = s >> 3, pc = s & 7, c = pc ^ (dr & 7);
            gload16(Vbb + (size_t)dr * 2048 + k0 + c * 8, sVb + s * 8);
        }
    };

    f32x4 o[2][8];
    #pragma unroll
    for (int rf = 0; rf < 2; ++rf)
        #pragma unroll
        for (int df = 0; df < 8; ++df) o[rf][df] = (f32x4)0.f;
    float m_[2][4], l_[2][4];
    #pragma unroll
    for (int rf = 0; rf < 2; ++rf)
        #pragma unroll
        for (int j = 0; j < 4; ++j) { m_[rf][j] = -__builtin_inff(); l_[rf][j] = 0.f; }

    int ntiles = (qt << 1) + 2;
    stageKV(0, 0);                       // prologue prefetch
    int cur = 0;
    for (int kt = 0; kt < ntiles; ++kt) {
        int k0 = kt * 64;
        bool dtile = (kt >= (qt << 1));  // diagonal (masked) tile — wave-uniform
        __syncthreads();                 // drains stage(kt) into buf cur
        if (kt + 1 < ntiles) stageKV(cur ^ 1, kt + 1);   // in flight under compute
        const ushort* sK = smem + cur * 8192;
        const ushort* sV = smem + 16384 + cur * 8192;

        // ---- S = Q K^T  (log2 domain: q carries 1/sqrt(d)*log2e)
        f32x4 s4[2][4];
        #pragma unroll
        for (int rf = 0; rf < 2; ++rf)
            #pragma unroll
            for (int kf = 0; kf < 4; ++kf) s4[rf][kf] = (f32x4)0.f;
        #pragma unroll
        for (int kf = 0; kf < 4; ++kf) {
            bf16x8 kfr[4];
            int krow = kf * 16 + lrow;
            #pragma unroll
            for (int ds = 0; ds < 4; ++ds) {
                int pc = (ds * 4 + lk) ^ (krow & 15);
                kfr[ds] = ldsr(sK + krow * 128 + pc * 8);
            }
            __builtin_amdgcn_s_setprio(1);
            #pragma unroll
            for (int rf = 0; rf < 2; ++rf)
                #pragma unroll
                for (int ds = 0; ds < 4; ++ds)
                    s4[rf][kf] = mfma16(qf[rf][ds], kfr[ds], s4[rf][kf]);
            __builtin_amdgcn_s_setprio(0);
        }

        // ---- pass 1: row maxes (mask diag tiles), wave growth vote (T13)
        float tmv[2][4];
        float growth = -3.4e38f;
        #pragma unroll
        for (int rf = 0; rf < 2; ++rf) {
            int qbase = q0 + w * 32 + rf * 16 + lk * 4;
            #pragma unroll
            for (int j = 0; j < 4; ++j) {
                float tm;
                if (dtile) {
                    int qg = qbase + j;
                    tm = -__builtin_inff();
                    #pragma unroll
                    for (int kf = 0; kf < 4; ++kf) {
                        int kg = k0 + kf * 16 + lrow;
                        float vv = (kg <= qg) ? s4[rf][kf][j] : -__builtin_inff();
                        s4[rf][kf][j] = vv;
                        tm = fmaxf(tm, vv);
                    }
                } else {
                    tm = fmaxf(fmaxf(s4[rf][0][j], s4[rf][1][j]),
                               fmaxf(s4[rf][2][j], s4[rf][3][j]));
                }
                tm = fmaxf(tm, __shfl_xor(tm, 1));
                tm = fmaxf(tm, __shfl_xor(tm, 2));
                tm = fmaxf(tm, __shfl_xor(tm, 4));
                tm = fmaxf(tm, __shfl_xor(tm, 8));
                tmv[rf][j] = tm;
                growth = fmaxf(growth, tm - m_[rf][j]);
            }
        }
        int defer = __all(growth <= 8.0f);   // wave-uniform; P bounded by 2^8

        // ---- pass 2: P = exp2(S - m), l update
        #pragma unroll
        for (int rf = 0; rf < 2; ++rf) {
            #pragma unroll
            for (int j = 0; j < 4; ++j) {
                float mold = m_[rf][j];
                float mnew, sc;
                if (defer) { mnew = mold; sc = 1.f; }
                else       { mnew = fmaxf(mold, tmv[rf][j]); sc = exp2f(mold - mnew); }
                float rs = 0.f;
                #pragma unroll
                for (int kf = 0; kf < 4; ++kf) {
                    float p = exp2f(s4[rf][kf][j] - mnew);  // masked -> exp2(-inf)=0
                    s4[rf][kf][j] = p;
                    rs += p;
                }
                rs += __shfl_xor(rs, 1); rs += __shfl_xor(rs, 2);
                rs += __shfl_xor(rs, 4); rs += __shfl_xor(rs, 8);
                l_[rf][j] = l_[rf][j] * sc + rs;
                m_[rf][j] = mnew;
                tmv[rf][j] = sc;   // reuse as scale for O-rescale
            }
        }
        if (!defer) {
            #pragma unroll
            for (int rf = 0; rf < 2; ++rf)
                #pragma unroll
                for (int df = 0; df < 8; ++df)
                    #pragma unroll
                    for (int j = 0; j < 4; ++j) o[rf][df][j] *= tmv[rf][j];
        }

        // ---- P -> per-wave LDS (bf16), swizzled [32][64]
        #pragma unroll
        for (int rf = 0; rf < 2; ++rf)
            #pragma unroll
            for (int kf = 0; kf < 4; ++kf)
                #pragma unroll
                for (int j = 0; j < 4; ++j) {
                    int row = rf * 16 + lk * 4 + j;
                    int kx = kf * 16 + lrow;
                    int pc = (kx >> 3) ^ (row & 7);
                    sP[row * 64 + pc * 8 + (kx & 7)] = f2b(s4[rf][kf][j]);
                }

        bf16x8 pf[2][2];
        #pragma unroll
        for (int rf = 0; rf < 2; ++rf)
            #pragma unroll
            for (int ks = 0; ks < 2; ++ks) {
                int row = rf * 16 + lrow;
                int pc = (ks * 4 + lk) ^ (row & 7);
                pf[rf][ks] = ldsr(sP + row * 64 + pc * 8);
            }

        // ---- O += P V
        #pragma unroll
        for (int df = 0; df < 8; ++df) {
            bf16x8 vfr[2];
            int d = df * 16 + lrow;
            #pragma unroll
            for (int ks = 0; ks < 2; ++ks) {
                int pc = (ks * 4 + lk) ^ (d & 7);
                vfr[ks] = ldsr(sV + d * 64 + pc * 8);
            }
            __builtin_amdgcn_s_setprio(1);
            #pragma unroll
            for (int rf = 0; rf < 2; ++rf)
                #pragma unroll
                for (int ks = 0; ks < 2; ++ks)
                    o[rf][df] = mfma16(pf[rf][ks], vfr[ks], o[rf][df]);
            __builtin_amdgcn_s_setprio(0);
        }
        cur ^= 1;
    }

    // ---- epilogue: O /= l, write bf16 attn_out (B,T,C)
    #pragma unroll
    for (int rf = 0; rf < 2; ++rf) {
        #pragma unroll
        for (int j = 0; j < 4; ++j) {
            int t = q0 + w * 32 + rf * 16 + lk * 4 + j;
            float inv = 1.f / l_[rf][j];
            #pragma unroll
            for (int df = 0; df < 8; ++df) {
                int d = df * 16 + lrow;
                O[(((size_t)b * 2048 + t) << 11) + (h << 7) + d] = f2b(o[rf][df][j] * inv);
            }
        }
    }
}

// ----------------------------------------------------------------------------
extern "C" void kernel_launch(void* const* d_in, const int* in_sizes, int n_in,
                              void* d_out, int out_size, void* d_ws, size_t ws_size,
                              hipStream_t stream)
{
    const float* x  = (const float*)d_in[0];
    const float* fc = (const float*)d_in[1];
    const float* fs = (const float*)d_in[2];
    // d_in[3] = mask (bool tril) — causal handled analytically
    const float* Wa = (const float*)d_in[4];
    const float* ba = (const float*)d_in[5];
    const float* Wp = (const float*)d_in[6];
    const float* bp = (const float*)d_in[7];
    float* out = (float*)d_out;

    char* ws = (char*)d_ws;
    size_t off = 0;
    auto alloc = [&](size_t bytes) { void* p = ws + off; off += (bytes + 255) & ~(size_t)255; return p; };
    // Liveness-aliased workspace (160 MB total):
    //   xb (x bf16) dead after GEMM1 -> reused as ao (attn out)
    //   vb is written directly in (B,H,HD,T) layout by GEMM1 (no transpose pass)
    ushort* xb  = (ushort*)alloc(8192UL * 2048 * 2);     // 32MB; later ao (B,T,C)
    ushort* WaT = (ushort*)alloc(6144UL * 2048 * 2);     // 24MB
    ushort* WpT = (ushort*)alloc(2048UL * 2048 * 2);     // 8MB
    ushort* qb  = (ushort*)alloc(64UL * 2048 * 128 * 2); // 32MB q (B,H,T,HD) scaled
    ushort* kb  = (ushort*)alloc(64UL * 2048 * 128 * 2); // 32MB k roped (B,H,T,HD)
    ushort* vb  = (ushort*)alloc(64UL * 2048 * 128 * 2); // 32MB v roped (B,H,HD,T)
    ushort* ao  = xb;   // alias: attn out bf16 (B,T,C)
    if (ws_size < off) return;  // workspace too small — fail loudly via validation

    k_cvt<<<8192, 256, 0, stream>>>(x, xb, 2097152);
    k_tr_w<<<dim3(192, 64), 256, 0, stream>>>(Wa, WaT, 2048, 6144);
    k_tr_w<<<dim3(64, 64), 256, 0, stream>>>(Wp, WpT, 2048, 2048);
    k_gemm<0><<<3072, 256, 0, stream>>>(xb, WaT, 8192, 48, 2048, 384,
                                        ba, qb, kb, vb, fc, fs, nullptr);
    k_attn<<<1024, 256, 0, stream>>>(qb, kb, vb, ao);
    k_gemm<1><<<1024, 256, 0, stream>>>(ao, WpT, 8192, 16, 2048, 128,
                                        bp, nullptr, nullptr, nullptr, nullptr, nullptr, out);
}